// Round 7
// baseline (934.940 us; speedup 1.0000x reference)
//
#include <hip/hip_runtime.h>

// Problem constants (fixed by setup_inputs; attn_num=5, d_delay=10 are python ints)
#define B_    1024
#define L_    512
#define H_    128
#define NIN_  2
#define ATTN_ 5
#define DLY_  10

typedef __bf16 bf16x8 __attribute__((ext_vector_type(8)));
typedef unsigned short ushort8 __attribute__((ext_vector_type(8)));
typedef float floatx4 __attribute__((ext_vector_type(4)));

__device__ __forceinline__ unsigned short f2bf(float f) {
  unsigned int x = __builtin_bit_cast(unsigned int, f);
  x += 0x7fffu + ((x >> 16) & 1u);          // RNE
  return (unsigned short)(x >> 16);
}
__device__ __forceinline__ float sigm(float x) { return 1.0f / (1.0f + __expf(-x)); }
// Pre-scaled sigmoid: y = -log2(e)*x already -> sigma(x) = rcp(1+exp2(y)).
__device__ __forceinline__ float sigp(float y) {
  return __builtin_amdgcn_rcpf(1.0f + __builtin_amdgcn_exp2f(y));
}
__device__ __forceinline__ floatx4 mfma16(bf16x8 a, bf16x8 b, floatx4 c) {
  return __builtin_amdgcn_mfma_f32_16x16x32_bf16(a, b, c, 0, 0, 0);
}

// Swizzled LDS layout for h matrices (ushort units): rows disjoint (stride
// 136 > 128); column rotation by 16 for rows 8..15 tiles the gate-dim b16
// scatter across all 32 banks (2 lanes/dword = free). Rotation is a multiple
// of 16 so 8/16-elem reads stay contiguous and 16B-aligned.
__device__ __forceinline__ int hoff(int r, int d) {
  return r * 136 + ((d + ((r & 8) << 1)) & 127);
}

// ---------------------------------------------------------------------------
// Fully-fused 2-layer GRU + local attention + decoder partials, persistent
// over 512 steps, one barrier per iteration. One block = 16 batch rows of one
// stack (128 blocks). Per iteration i:
//   layer0 t=i     : 12 MFMAs on h0(i-1)            (issued first)
//   layer1 t=i-1   : 24 MFMAs on h0(i-1), h1(i-2)   (issued second)
//   layer0 update  : trans-heavy VALU — overlaps layer1's MFMAs in the pipe
//   layer1 update  : writes h1(i-1) into a 12-slot LDS ring
// Every 8th iteration (i&7==1), a burst amortizes attention:
//   dots: wave w -> tau=i-9+w: 4 MFMAs h1(tau) @ [wa_p|u1|u2|wo] -> SR ring
//   softmax+dec for ps i-17..i-10 (waves 0-1; reads taus <= i-10 only).
// SR ring is 32 slots: in-burst writes cover taus [i-9,i-2] while softmax
// reads taus [i-22,i-10] with NO barrier between — write-read tau distance
// spans [12,20], so a 16-slot ring aliased (Round-6 bug: 16 | distance 16);
// 32 slots never alias and liveness holds (overwrite at ~tau+34 > last read
// at tau+22). Input staged in a double-buffered 64-step LDS chunk, prefetched
// mid-chunk with NO extra barrier. Final tiny kernel applies delay + sigmoid.
// ---------------------------------------------------------------------------
__global__ __launch_bounds__(512, 2)
void gru_stack_kernel(
    const float* __restrict__ recv,
    const float* __restrict__ wih0_1, const float* __restrict__ whh0_1,
    const float* __restrict__ bih0_1, const float* __restrict__ bhh0_1,
    const float* __restrict__ wih1_1, const float* __restrict__ whh1_1,
    const float* __restrict__ bih1_1, const float* __restrict__ bhh1_1,
    const float* __restrict__ wih0_2, const float* __restrict__ whh0_2,
    const float* __restrict__ bih0_2, const float* __restrict__ bhh0_2,
    const float* __restrict__ wih1_2, const float* __restrict__ whh1_2,
    const float* __restrict__ bih1_2, const float* __restrict__ bhh1_2,
    const float* __restrict__ w_a, const float* __restrict__ w_c,
    const float* __restrict__ b_c, const float* __restrict__ w_o,
    float* __restrict__ dec1, float* __restrict__ dec2)
{
  const int bid  = blockIdx.x;        // 0..127
  const int stk  = bid >> 6;          // 0: stack1, 1: stack2
  const int b0   = (bid & 63) * 16;
  const int tid  = threadIdx.x;
  const int wave = tid >> 6;
  const int lane = tid & 63;
  const int lcol = lane & 15;
  const int lquad = lane >> 4;
  const int dim  = 16 * wave + lcol;  // gate dim this lane owns (D-layout col)

  const float* wih0 = stk ? wih0_2 : wih0_1;
  const float* whh0 = stk ? whh0_2 : whh0_1;
  const float* bih0 = stk ? bih0_2 : bih0_1;
  const float* bhh0 = stk ? bhh0_2 : bhh0_1;
  const float* wih1 = stk ? wih1_2 : wih1_1;
  const float* whh1 = stk ? whh1_2 : whh1_1;
  const float* bih1 = stk ? bih1_2 : bih1_1;
  const float* bhh1 = stk ? bhh1_2 : bhh1_1;
  float* dout = stk ? dec2 : dec1;

  __shared__ __attribute__((aligned(16))) unsigned short h0L[2][2176];   // dbuf
  __shared__ __attribute__((aligned(16))) unsigned short h1R[12][2176];  // ring
  __shared__ __attribute__((aligned(16))) float xs[2][16][132];          // input, dbuf
  __shared__ __attribute__((aligned(16))) float SR[4][32][16];  // scalar rings: s_p,q1,q2,q0
  __shared__ __attribute__((aligned(16))) float decring[16][8];
  __shared__ float waL[256];   // w_a
  __shared__ float woL[128];   // wo half for this stack
  __shared__ float uL[256];    // u1 | u2
  __shared__ float red[128];
  __shared__ float CcL;

  const float S1 = -1.4426950408889634f;   // -log2(e)   (r,z gates)
  const float S2 = -2.8853900817779268f;   // -2*log2(e) (n gate)

  // --- loop-invariant weight B-fragments in registers (pre-scaled) ---
  bf16x8 Whh0[3][4], Wih1[3][4], Whh1[3][4];
  {
#pragma unroll
    for (int ti = 0; ti < 3; ++ti) {
      const float sc = (ti == 2) ? S2 : S1;
      const int g = ti * 128 + dim;   // B-frag n index
#pragma unroll
      for (int ks = 0; ks < 4; ++ks) {
        const float* s0 = whh0 + g * H_ + ks * 32 + lquad * 8;
        const float* s1 = wih1 + g * H_ + ks * 32 + lquad * 8;
        const float* s2 = whh1 + g * H_ + ks * 32 + lquad * 8;
        ushort8 u0, u1, u2;
#pragma unroll
        for (int j = 0; j < 8; ++j) {
          u0[j] = f2bf(s0[j] * sc); u1[j] = f2bf(s1[j] * sc); u2[j] = f2bf(s2[j] * sc);
        }
        Whh0[ti][ks] = __builtin_bit_cast(bf16x8, u0);
        Wih1[ti][ks] = __builtin_bit_cast(bf16x8, u1);
        Whh1[ti][ks] = __builtin_bit_cast(bf16x8, u2);
      }
    }
  }
  // --- per-lane loop-invariant scalars (pre-scaled) ---
  const float wr0 = wih0[dim * 2] * S1,         wr1 = wih0[dim * 2 + 1] * S1;
  const float wz0 = wih0[(128 + dim) * 2] * S1, wz1 = wih0[(128 + dim) * 2 + 1] * S1;
  const float wn0 = wih0[(256 + dim) * 2] * S2, wn1 = wih0[(256 + dim) * 2 + 1] * S2;
  const float br0 = (bih0[dim] + bhh0[dim]) * S1;
  const float bz0 = (bih0[128 + dim] + bhh0[128 + dim]) * S1;
  const float bin0 = bih0[256 + dim] * S2, bhn0 = bhh0[256 + dim] * S2;
  const float br1 = (bih1[dim] + bhh1[dim]) * S1;
  const float bz1 = (bih1[128 + dim] + bhh1[128 + dim]) * S1;
  const float bin1 = bih1[256 + dim] * S2, bhn1 = bhh1[256 + dim] * S2;

  const int srow = tid >> 5;             // staging: 32 threads/row
  const int scol = (tid & 31) * 4;

  // --- init phase 0: stage small vectors, zero h, load input chunk 0 ---
  for (int i = tid; i < 256; i += 512) waL[i] = w_a[i];
  if (tid < 128) { woL[tid] = w_o[stk * 128 + tid]; }
  for (int i = tid; i < 2 * 2176; i += 512) ((unsigned short*)h0L)[i] = 0;
  for (int i = tid; i < 12 * 2176; i += 512) ((unsigned short*)h1R)[i] = 0;
  {
    const float4 v = *(const float4*)&recv[(size_t)(b0 + srow) * (L_ * NIN_) + scol];
    *(float4*)&xs[0][srow][scol] = v;
  }
  __syncthreads();
  // --- init phase 1: u vectors (u[d]=sum_m wc[m, off+d]*wo_h[m]) and Cc ---
  {
    const int task = tid >> 1, sub = tid & 1;       // task: 0..255
    const int which = task >> 7, d = task & 127;
    float acc = 0.f;
    const float* wcp = w_c + which * 128 + d + sub * 64 * 256;
    for (int m = 0; m < 64; ++m) acc += wcp[m * 256] * woL[sub * 64 + m];
    acc += __shfl_xor(acc, 1);
    if (sub == 0) uL[task] = acc;
  }
  if (tid < 128) red[tid] = b_c[tid] * woL[tid];
  __syncthreads();
  if (tid < 64) {
    float v = red[tid] + red[tid + 64];
    v += __shfl_xor(v, 1); v += __shfl_xor(v, 2); v += __shfl_xor(v, 4);
    v += __shfl_xor(v, 8); v += __shfl_xor(v, 16); v += __shfl_xor(v, 32);
    if (tid == 0) CcL = v;
  }
  __syncthreads();
  const float Cc = CcL;
  // --- dot-MFMA B-fragment: cols 0..3 = wa_p | u1 | u2 | wo_h ---
  bf16x8 Vb[4];
  {
#pragma unroll
    for (int ks = 0; ks < 4; ++ks) {
      ushort8 u;
#pragma unroll
      for (int j = 0; j < 8; ++j) {
        const int k = ks * 32 + lquad * 8 + j;
        float v = 0.f;
        if (lcol == 0) v = waL[128 + k];
        else if (lcol == 1) v = uL[k];
        else if (lcol == 2) v = uL[128 + k];
        else if (lcol == 3) v = woL[k];
        u[j] = f2bf(v);
      }
      Vb[ks] = __builtin_bit_cast(bf16x8, u);
    }
  }

  float h0m[4] = {0.f, 0.f, 0.f, 0.f};   // fp32 master h, rows lquad*4+j, col dim
  float h1m[4] = {0.f, 0.f, 0.f, 0.f};

  const int hAbase = lcol * 136;         // A-fragment read addressing
  int aofs[4];
#pragma unroll
  for (int ks = 0; ks < 4; ++ks)
    aofs[ks] = ((ks * 32 + lquad * 8 + ((lcol & 8) << 1)) & 127);
  int wofs[4];
#pragma unroll
  for (int j = 0; j < 4; ++j) wofs[j] = hoff(lquad * 4 + j, dim);

  for (int i = 0; i <= L_ + 9; ++i) {    // 512 steps + drain/burst tail
    const int rb = i & 1, wb = rb ^ 1;   // h0 dbuf parity
    // barrier-free input prefetch: mid-chunk, next chunk into other buffer
    if ((i & 63) == 32 && i < 448) {
      const int c = (i >> 6) + 1;
      const float4 v = *(const float4*)&recv[(size_t)(b0 + srow) * (L_ * NIN_) + (c << 6) * NIN_ + scol];
      *(float4*)&xs[c & 1][srow][scol] = v;
    }

    const bool do0 = (i < L_);
    const bool do1 = (i >= 1 && i <= L_);
    const int r12 = (i + 10) % 12;       // h1(i-2) ring slot
    const int w12 = (i + 11) % 12;       // h1(i-1) ring slot

    floatx4 aR = {0.f,0.f,0.f,0.f}, aZ = {0.f,0.f,0.f,0.f}, aN = {0.f,0.f,0.f,0.f};
    floatx4 bR = {0.f,0.f,0.f,0.f}, bZ = {0.f,0.f,0.f,0.f};
    floatx4 bGi = {0.f,0.f,0.f,0.f}, bGh = {0.f,0.f,0.f,0.f};
    if (do0) {
      // ---- layer0 gates (issued FIRST so their update overlaps layer1 MFMAs) ----
#pragma unroll
      for (int ks = 0; ks < 4; ++ks) {
        const bf16x8 a0 = *(const bf16x8*)&h0L[rb][hAbase + aofs[ks]];
        aR = mfma16(a0, Whh0[0][ks], aR);
        aZ = mfma16(a0, Whh0[1][ks], aZ);
        aN = mfma16(a0, Whh0[2][ks], aN);
      }
    }
    if (do1) {
      // ---- layer1 gates ----
#pragma unroll
      for (int ks = 0; ks < 4; ++ks) {
        const bf16x8 a0 = *(const bf16x8*)&h0L[rb][hAbase + aofs[ks]];
        bR  = mfma16(a0, Wih1[0][ks], bR);
        bZ  = mfma16(a0, Wih1[1][ks], bZ);
        bGi = mfma16(a0, Wih1[2][ks], bGi);
      }
#pragma unroll
      for (int ks = 0; ks < 4; ++ks) {
        const bf16x8 a1 = *(const bf16x8*)&h1R[r12][hAbase + aofs[ks]];
        bR  = mfma16(a1, Whh1[0][ks], bR);
        bZ  = mfma16(a1, Whh1[1][ks], bZ);
        bGh = mfma16(a1, Whh1[2][ks], bGh);
      }
    }
    if (do0) {
      // ---- layer0 update (t=i): overlaps layer1 MFMA pipe time ----
      const int tl = i & 63, cb = (i >> 6) & 1;
#pragma unroll
      for (int j = 0; j < 4; ++j) {
        const float2 xv = *(const float2*)&xs[cb][lquad * 4 + j][2 * tl];
        const float rg = sigp(fmaf(xv.x, wr0, fmaf(xv.y, wr1, aR[j] + br0)));
        const float zg = sigp(fmaf(xv.x, wz0, fmaf(xv.y, wz1, aZ[j] + bz0)));
        const float ng = fmaf(2.f, sigp(fmaf(rg, aN[j] + bhn0,
                              fmaf(xv.x, wn0, fmaf(xv.y, wn1, bin0)))), -1.f);
        h0m[j] = fmaf(zg, h0m[j] - ng, ng);
        h0L[wb][wofs[j]] = f2bf(h0m[j]);
      }
    }
    if (do1) {
      // ---- layer1 update (t=i-1) -> h1 ring ----
#pragma unroll
      for (int j = 0; j < 4; ++j) {
        const float rg = sigp(bR[j] + br1);
        const float zg = sigp(bZ[j] + bz1);
        const float ng = fmaf(2.f, sigp(fmaf(rg, bGh[j] + bhn1, bGi[j] + bin1)), -1.f);
        h1m[j] = fmaf(zg, h1m[j] - ng, ng);
        h1R[w12][wofs[j]] = f2bf(h1m[j]);
      }
    }

    // ---- 8-step attention burst ----
    if ((i & 7) == 1) {
      // dots: one tau per wave, taus i-9..i-2 (h1 ring, all synced)
      const int tau = i - 9 + wave;
      if (i >= 9 && tau < L_) {
        const int hs = tau % 12;
        floatx4 d = {0.f,0.f,0.f,0.f};
#pragma unroll
        for (int ks = 0; ks < 4; ++ks)
          d = mfma16(*(const bf16x8*)&h1R[hs][hAbase + aofs[ks]], Vb[ks], d);
        if (lcol < 4)
          *(floatx4*)&SR[lcol][tau & 31][lquad * 4] = d;
      }
      // softmax + dec for ps i-17..i-10 (only reads taus <= i-10: prior bursts;
      // 32-slot ring guarantees no aliasing with this burst's writes)
      if (i >= 17 && tid < 128) {
        const int row = tid >> 3, pj = tid & 7, p = i - 17 + pj;
        float dec;
        if (p >= ATTN_) {
          float e[ATTN_], mx = -1e30f;
#pragma unroll
          for (int j = 0; j < ATTN_; ++j) { e[j] = SR[0][(p - 5 + j) & 31][row]; mx = fmaxf(mx, e[j]); }
          float s = 0.f, q = 0.f;
#pragma unroll
          for (int j = 0; j < ATTN_; ++j) {
            const float w = __expf(e[j] - mx);
            s += w;
            q = fmaf(w, SR[1][(p - 5 + j) & 31][row], q);
          }
          dec = q * __builtin_amdgcn_rcpf(s) + SR[2][p & 31][row] + Cc;
        } else {
          dec = SR[3][p & 31][row];               // passthrough: r[p].wo_half
        }
        decring[row][pj] = dec;
        if (pj < 2) {   // row's 8 values live in this same wave -> no barrier
          const float4 v = *(const float4*)&decring[row][pj * 4];
          *(float4*)&dout[(size_t)(b0 + row) * L_ + (i - 17) + pj * 4] = v;
        }
      }
    }
    __syncthreads();
  }
}

// ---------------------------------------------------------------------------
// Final combine: out[b,t] = sigmoid(dec1[b,t] + dec2[b,min(t+10,511)] + b_o)
// ---------------------------------------------------------------------------
__global__ __launch_bounds__(512)
void combine_kernel(const float* __restrict__ dec1, const float* __restrict__ dec2,
                    const float* __restrict__ b_o, float* __restrict__ out)
{
  const int b = blockIdx.x, t = threadIdx.x;
  const int dt = (t + DLY_ < L_) ? t + DLY_ : L_ - 1;
  out[(size_t)b * L_ + t] = sigm(dec1[(size_t)b * L_ + t] + dec2[(size_t)b * L_ + dt] + b_o[0]);
}

extern "C" void kernel_launch(void* const* d_in, const int* in_sizes, int n_in,
                              void* d_out, int out_size, void* d_ws, size_t ws_size,
                              hipStream_t stream) {
  const float* recv   = (const float*)d_in[0];
  const float* wih1l0 = (const float*)d_in[1];
  const float* whh1l0 = (const float*)d_in[2];
  const float* bih1l0 = (const float*)d_in[3];
  const float* bhh1l0 = (const float*)d_in[4];
  const float* wih1l1 = (const float*)d_in[5];
  const float* whh1l1 = (const float*)d_in[6];
  const float* bih1l1 = (const float*)d_in[7];
  const float* bhh1l1 = (const float*)d_in[8];
  const float* wih2l0 = (const float*)d_in[9];
  const float* whh2l0 = (const float*)d_in[10];
  const float* bih2l0 = (const float*)d_in[11];
  const float* bhh2l0 = (const float*)d_in[12];
  const float* wih2l1 = (const float*)d_in[13];
  const float* whh2l1 = (const float*)d_in[14];
  const float* bih2l1 = (const float*)d_in[15];
  const float* bhh2l1 = (const float*)d_in[16];
  const float* w_a    = (const float*)d_in[17];
  const float* b_a    = (const float*)d_in[18]; (void)b_a; // uniform: cancels in softmax
  const float* w_c    = (const float*)d_in[19];
  const float* b_c    = (const float*)d_in[20];
  const float* w_o    = (const float*)d_in[21];
  const float* b_o    = (const float*)d_in[22];
  // d_in[23]=attn_num(5), d_in[24]=d_delay(10): compile-time constants here

  float* dec1 = (float*)d_ws;                 // (B,L) fp32 decoder partial, stack1
  float* dec2 = dec1 + (size_t)B_ * L_;       // (B,L) fp32 decoder partial, stack2

  gru_stack_kernel<<<128, 512, 0, stream>>>(
      recv,
      wih1l0, whh1l0, bih1l0, bhh1l0, wih1l1, whh1l1, bih1l1, bhh1l1,
      wih2l0, whh2l0, bih2l0, bhh2l0, wih2l1, whh2l1, bih2l1, bhh2l1,
      w_a, w_c, b_c, w_o, dec1, dec2);

  combine_kernel<<<B_, 512, 0, stream>>>(dec1, dec2, b_o, (float*)d_out);
}

// Round 8
// 830.112 us; speedup vs baseline: 1.1263x; 1.1263x over previous
//
#include <hip/hip_runtime.h>

// Problem constants (fixed by setup_inputs; attn_num=5, d_delay=10 are python ints)
#define B_    1024
#define L_    512
#define H_    128
#define NIN_  2
#define ATTN_ 5
#define DLY_  10

typedef __bf16 bf16x8 __attribute__((ext_vector_type(8)));
typedef unsigned short ushort8 __attribute__((ext_vector_type(8)));
typedef float floatx4 __attribute__((ext_vector_type(4)));

__device__ __forceinline__ unsigned short f2bf(float f) {
  unsigned int x = __builtin_bit_cast(unsigned int, f);
  x += 0x7fffu + ((x >> 16) & 1u);          // RNE
  return (unsigned short)(x >> 16);
}
__device__ __forceinline__ float sigm(float x) { return 1.0f / (1.0f + __expf(-x)); }
// Pre-scaled sigmoid: y = -log2(e)*x already -> sigma(x) = rcp(1+exp2(y)).
__device__ __forceinline__ float sigp(float y) {
  return __builtin_amdgcn_rcpf(1.0f + __builtin_amdgcn_exp2f(y));
}
__device__ __forceinline__ floatx4 mfma16(bf16x8 a, bf16x8 b, floatx4 c) {
  return __builtin_amdgcn_mfma_f32_16x16x32_bf16(a, b, c, 0, 0, 0);
}

// Swizzled LDS layout for h matrices (ushort units): rows disjoint (stride
// 136 > 128); column rotation by 16 for rows 8..15 tiles the gate-dim b16
// scatter across all 32 banks (2 lanes/dword = free). Rotation is a multiple
// of 16 so 8/16-elem reads stay contiguous and 16B-aligned.
__device__ __forceinline__ int hoff(int r, int d) {
  return r * 136 + ((d + ((r & 8) << 1)) & 127);
}

// ---------------------------------------------------------------------------
// LAYER-SPLIT persistent kernel: 1024 threads = 16 waves (4/SIMD for latency
// hiding). Waves 0-7 ("L0"): layer0 for gate-dim tile w — 12 MFMAs + update.
// Waves 8-15 ("L1"): layer1 for tile w-8 — 24 MFMAs + update. L1's weight
// set exceeds the 128-VGPR budget at 4 waves/SIMD, so Whh1 (r,z,n) + Wih1(n)
// live in registers and Wih1(r,z) fragments live in LDS (re-read 8xb128/step).
// Same proven skew-1 schedule as R5: at iter i, L0 computes t=i from
// h0(i-1); L1 computes t=i-1 from h0(i-1), h1(i-2); one barrier per iter.
// Attention per-step (R5-proven): wave0 dot on h1(i-2) -> SR scalar rings
// (s_p,q1,q2,q0); wave1 softmax+dec for p=i-3 (b_a/s_h cancel in softmax),
// dec partials burst-stored every 8 steps. Final tiny kernel: delay+sigmoid.
// ---------------------------------------------------------------------------
__global__ __launch_bounds__(1024, 1)
void gru_stack_kernel(
    const float* __restrict__ recv,
    const float* __restrict__ wih0_1, const float* __restrict__ whh0_1,
    const float* __restrict__ bih0_1, const float* __restrict__ bhh0_1,
    const float* __restrict__ wih1_1, const float* __restrict__ whh1_1,
    const float* __restrict__ bih1_1, const float* __restrict__ bhh1_1,
    const float* __restrict__ wih0_2, const float* __restrict__ whh0_2,
    const float* __restrict__ bih0_2, const float* __restrict__ bhh0_2,
    const float* __restrict__ wih1_2, const float* __restrict__ whh1_2,
    const float* __restrict__ bih1_2, const float* __restrict__ bhh1_2,
    const float* __restrict__ w_a, const float* __restrict__ w_c,
    const float* __restrict__ b_c, const float* __restrict__ w_o,
    float* __restrict__ dec1, float* __restrict__ dec2)
{
  const int bid  = blockIdx.x;        // 0..127
  const int stk  = bid >> 6;          // 0: stack1, 1: stack2
  const int b0   = (bid & 63) * 16;
  const int tid  = threadIdx.x;
  const int wv   = tid >> 6;          // 0..15
  const int lane = tid & 63;
  const int lcol = lane & 15;
  const int lquad = lane >> 4;
  const bool isL0 = (wv < 8);
  const int tile = isL0 ? wv : (wv - 8);
  const int dim  = tile * 16 + lcol;  // gate dim this lane owns

  const float* wih0 = stk ? wih0_2 : wih0_1;
  const float* whh0 = stk ? whh0_2 : whh0_1;
  const float* bih0 = stk ? bih0_2 : bih0_1;
  const float* bhh0 = stk ? bhh0_2 : bhh0_1;
  const float* wih1 = stk ? wih1_2 : wih1_1;
  const float* whh1 = stk ? whh1_2 : whh1_1;
  const float* bih1 = stk ? bih1_2 : bih1_1;
  const float* bhh1 = stk ? bhh1_2 : bhh1_1;
  float* dout = stk ? dec2 : dec1;

  __shared__ __attribute__((aligned(16))) unsigned short h0L[2][2176];   // dbuf
  __shared__ __attribute__((aligned(16))) unsigned short h1L[2][2176];   // dbuf
  __shared__ __attribute__((aligned(16))) unsigned short wihL[32768];    // Wih1 r,z frags (64 KB)
  __shared__ __attribute__((aligned(16))) float xs[2][16][132];          // input, dbuf
  __shared__ __attribute__((aligned(16))) float SR[4][8][16];  // scalar rings: s_p,q1,q2,q0
  __shared__ __attribute__((aligned(16))) float decring[16][8];
  __shared__ float waL[256];   // w_a
  __shared__ float woL[128];   // wo half for this stack
  __shared__ float uL[256];    // u1 | u2
  __shared__ float red[128];
  __shared__ float CcL;

  const float S1 = -1.4426950408889634f;   // -log2(e)   (r,z gates)
  const float S2 = -2.8853900817779268f;   // -2*log2(e) (n gate)

  // --- weight fragments (pre-scaled). Wreg: L0=Whh0, L1=Whh1.
  //     Xtra: wave0=dot vectors Vb (filled later), L1=Wih1 n-gate. ---
  bf16x8 Wreg[3][4];
  bf16x8 Xtra[4];
  if (isL0) {
#pragma unroll
    for (int ti = 0; ti < 3; ++ti) {
      const float sc = (ti == 2) ? S2 : S1;
      const int g = ti * 128 + dim;
#pragma unroll
      for (int ks = 0; ks < 4; ++ks) {
        const float* s0 = whh0 + g * H_ + ks * 32 + lquad * 8;
        ushort8 u0;
#pragma unroll
        for (int j = 0; j < 8; ++j) u0[j] = f2bf(s0[j] * sc);
        Wreg[ti][ks] = __builtin_bit_cast(bf16x8, u0);
      }
    }
  } else {
#pragma unroll
    for (int ti = 0; ti < 3; ++ti) {
      const float sc = (ti == 2) ? S2 : S1;
      const int g = ti * 128 + dim;
#pragma unroll
      for (int ks = 0; ks < 4; ++ks) {
        const float* s2 = whh1 + g * H_ + ks * 32 + lquad * 8;
        ushort8 u2;
#pragma unroll
        for (int j = 0; j < 8; ++j) u2[j] = f2bf(s2[j] * sc);
        Wreg[ti][ks] = __builtin_bit_cast(bf16x8, u2);
      }
    }
    // Wih1 n-gate -> registers (Xtra)
#pragma unroll
    for (int ks = 0; ks < 4; ++ks) {
      const float* s1 = wih1 + (256 + dim) * H_ + ks * 32 + lquad * 8;
      ushort8 u1;
#pragma unroll
      for (int j = 0; j < 8; ++j) u1[j] = f2bf(s1[j] * S2);
      Xtra[ks] = __builtin_bit_cast(bf16x8, u1);
    }
    // Wih1 r,z gates -> LDS fragment slabs [tile][g][ks][lane][8]
#pragma unroll
    for (int g = 0; g < 2; ++g) {
#pragma unroll
      for (int ks = 0; ks < 4; ++ks) {
        const float* s1 = wih1 + (g * 128 + dim) * H_ + ks * 32 + lquad * 8;
        ushort8 u1;
#pragma unroll
        for (int j = 0; j < 8; ++j) u1[j] = f2bf(s1[j] * S1);
        *(ushort8*)&wihL[((((tile * 2 + g) * 4 + ks) << 6) + lane) << 3] =
            __builtin_bit_cast(ushort8, u1);
      }
    }
  }
  // --- per-lane loop-invariant scalars (branch-shared names, pre-scaled) ---
  float c0, c1, c2, c3, c4, c5, c6, c7, c8, c9;
  if (isL0) {
    c0 = wih0[dim * 2] * S1;         c1 = wih0[dim * 2 + 1] * S1;          // wr0 wr1
    c2 = wih0[(128 + dim) * 2] * S1; c3 = wih0[(128 + dim) * 2 + 1] * S1;  // wz0 wz1
    c4 = wih0[(256 + dim) * 2] * S2; c5 = wih0[(256 + dim) * 2 + 1] * S2;  // wn0 wn1
    c6 = (bih0[dim] + bhh0[dim]) * S1;                                     // br0
    c7 = (bih0[128 + dim] + bhh0[128 + dim]) * S1;                         // bz0
    c8 = bih0[256 + dim] * S2;       c9 = bhh0[256 + dim] * S2;            // bin0 bhn0
  } else {
    c0 = (bih1[dim] + bhh1[dim]) * S1;                                     // br1
    c1 = (bih1[128 + dim] + bhh1[128 + dim]) * S1;                         // bz1
    c2 = bih1[256 + dim] * S2;       c3 = bhh1[256 + dim] * S2;            // bin1 bhn1
    c4 = c5 = c6 = c7 = c8 = c9 = 0.f;
  }

  // --- init phase 0: small vectors, zero h, stage input chunk 0 ---
  for (int i = tid; i < 256; i += 1024) waL[i] = w_a[i];
  if (tid < 128) woL[tid] = w_o[stk * 128 + tid];
  for (int i = tid; i < 2 * 2176; i += 1024) { ((unsigned short*)h0L)[i] = 0; ((unsigned short*)h1L)[i] = 0; }
  {
    const int row = tid >> 6, col = (tid & 63) * 2;
    const float2 v = *(const float2*)&recv[(size_t)(b0 + row) * (L_ * NIN_) + col];
    *(float2*)&xs[0][row][col] = v;
  }
  __syncthreads();
  // --- init phase 1: u vectors and Cc ---
  if (tid < 512) {
    const int task = tid >> 1, sub = tid & 1;       // task: 0..255
    const int which = task >> 7, d = task & 127;
    float acc = 0.f;
    const float* wcp = w_c + which * 128 + d + sub * 64 * 256;
    for (int m = 0; m < 64; ++m) acc += wcp[m * 256] * woL[sub * 64 + m];
    acc += __shfl_xor(acc, 1);
    if (sub == 0) uL[task] = acc;
  }
  if (tid < 128) red[tid] = b_c[tid] * woL[tid];
  __syncthreads();
  if (tid < 64) {
    float v = red[tid] + red[tid + 64];
    v += __shfl_xor(v, 1); v += __shfl_xor(v, 2); v += __shfl_xor(v, 4);
    v += __shfl_xor(v, 8); v += __shfl_xor(v, 16); v += __shfl_xor(v, 32);
    if (tid == 0) CcL = v;
  }
  __syncthreads();
  const float Cc = CcL;
  // --- wave0: dot-MFMA B-fragment into Xtra: cols 0..3 = wa_p | u1 | u2 | wo_h ---
  if (wv == 0) {
#pragma unroll
    for (int ks = 0; ks < 4; ++ks) {
      ushort8 u;
#pragma unroll
      for (int j = 0; j < 8; ++j) {
        const int k = ks * 32 + lquad * 8 + j;
        float v = 0.f;
        if (lcol == 0) v = waL[128 + k];
        else if (lcol == 1) v = uL[k];
        else if (lcol == 2) v = uL[128 + k];
        else if (lcol == 3) v = woL[k];
        u[j] = f2bf(v);
      }
      Xtra[ks] = __builtin_bit_cast(bf16x8, u);
    }
  }

  float hm[4] = {0.f, 0.f, 0.f, 0.f};    // fp32 master h (L0: h0; L1: h1)

  const int hAbase = lcol * 136;         // A-fragment read addressing
  int aofs[4];
#pragma unroll
  for (int ks = 0; ks < 4; ++ks)
    aofs[ks] = ((ks * 32 + lquad * 8 + ((lcol & 8) << 1)) & 127);
  int wofs[4];
#pragma unroll
  for (int j = 0; j < 4; ++j) wofs[j] = hoff(lquad * 4 + j, dim);

  for (int i = 0; i <= L_ + 2; ++i) {
    const int rb = i & 1, wb = rb ^ 1;
    // barrier-free input prefetch: mid-chunk, next chunk into other buffer
    if ((i & 63) == 32 && i < 448) {
      const int c = (i >> 6) + 1;
      const int row = tid >> 6, col = (tid & 63) * 2;
      const float2 v = *(const float2*)&recv[(size_t)(b0 + row) * (L_ * NIN_) + (c << 6) * NIN_ + col];
      *(float2*)&xs[c & 1][row][col] = v;
    }

    if (isL0) {
      floatx4 aR = {0.f,0.f,0.f,0.f}, aZ = {0.f,0.f,0.f,0.f}, aN = {0.f,0.f,0.f,0.f};
      const bool doA = (i < L_);
      if (doA) {
#pragma unroll
        for (int ks = 0; ks < 4; ++ks) {
          const bf16x8 a0 = *(const bf16x8*)&h0L[rb][hAbase + aofs[ks]];
          aR = mfma16(a0, Wreg[0][ks], aR);
          aZ = mfma16(a0, Wreg[1][ks], aZ);
          aN = mfma16(a0, Wreg[2][ks], aN);
        }
      }
      // wave0: attention dot for tau=i-2 on h1(i-2)
      if (wv == 0 && i >= 2 && i <= L_ + 1) {
        floatx4 d = {0.f,0.f,0.f,0.f};
#pragma unroll
        for (int ks = 0; ks < 4; ++ks)
          d = mfma16(*(const bf16x8*)&h1L[rb][hAbase + aofs[ks]], Xtra[ks], d);
        if (lcol < 4)
          *(floatx4*)&SR[lcol][(i - 2) & 7][lquad * 4] = d;
      }
      if (doA) {
        // layer0 update (t=i)
        const int tl = i & 63, cb = (i >> 6) & 1;
#pragma unroll
        for (int j = 0; j < 4; ++j) {
          const float2 xv = *(const float2*)&xs[cb][lquad * 4 + j][2 * tl];
          const float rg = sigp(fmaf(xv.x, c0, fmaf(xv.y, c1, aR[j] + c6)));
          const float zg = sigp(fmaf(xv.x, c2, fmaf(xv.y, c3, aZ[j] + c7)));
          const float ng = fmaf(2.f, sigp(fmaf(rg, aN[j] + c9,
                                fmaf(xv.x, c4, fmaf(xv.y, c5, c8)))), -1.f);
          hm[j] = fmaf(zg, hm[j] - ng, ng);
          h0L[wb][wofs[j]] = f2bf(hm[j]);
        }
      }
      // wave1: softmax + dec for p=i-3 (R5-proven ring distances)
      if (wv == 1 && lane < 16 && i >= 3) {
        const int p = i - 3, slot = p & 7, row = lane;
        float dec;
        if (p >= ATTN_) {
          float e[ATTN_], mx = -1e30f;
#pragma unroll
          for (int j = 0; j < ATTN_; ++j) { e[j] = SR[0][(p - 5 + j) & 7][row]; mx = fmaxf(mx, e[j]); }
          float s = 0.f, q = 0.f;
#pragma unroll
          for (int j = 0; j < ATTN_; ++j) {
            const float w = __expf(e[j] - mx);
            s += w;
            q = fmaf(w, SR[1][(p - 5 + j) & 7][row], q);
          }
          dec = q * __builtin_amdgcn_rcpf(s) + SR[2][slot][row] + Cc;
        } else {
          dec = SR[3][slot][row];               // passthrough: r[p].wo_half
        }
        decring[row][slot] = dec;
        if (slot == 7) {                        // burst-store 8 positions
          const float4 v0 = *(const float4*)&decring[row][0];
          const float4 v1 = *(const float4*)&decring[row][4];
          float* dst = dout + (size_t)(b0 + row) * L_ + (p - 7);
          *(float4*)dst = v0;
          *(float4*)(dst + 4) = v1;
        }
      }
    } else {
      // ---- L1 wave: layer1 t=i-1 ----
      if (i >= 1 && i <= L_) {
        floatx4 bR = {0.f,0.f,0.f,0.f}, bZ = {0.f,0.f,0.f,0.f};
        floatx4 bGi = {0.f,0.f,0.f,0.f}, bGh = {0.f,0.f,0.f,0.f};
        const int wbase = ((tile * 2) << 8);   // (tile*2+g)*4*64*8 with g=0 base, in ushorts<<3
#pragma unroll
        for (int ks = 0; ks < 4; ++ks) {
          const bf16x8 a0 = *(const bf16x8*)&h0L[rb][hAbase + aofs[ks]];  // h0(i-1)
          const bf16x8 a1 = *(const bf16x8*)&h1L[rb][hAbase + aofs[ks]];  // h1(i-2)
          const bf16x8 wr = *(const bf16x8*)&wihL[((((tile * 2 + 0) * 4 + ks) << 6) + lane) << 3];
          const bf16x8 wz = *(const bf16x8*)&wihL[((((tile * 2 + 1) * 4 + ks) << 6) + lane) << 3];
          bR  = mfma16(a0, wr, bR);
          bR  = mfma16(a1, Wreg[0][ks], bR);
          bZ  = mfma16(a0, wz, bZ);
          bZ  = mfma16(a1, Wreg[1][ks], bZ);
          bGi = mfma16(a0, Xtra[ks], bGi);
          bGh = mfma16(a1, Wreg[2][ks], bGh);
        }
        (void)wbase;
        // layer1 update (t=i-1)
#pragma unroll
        for (int j = 0; j < 4; ++j) {
          const float rg = sigp(bR[j] + c0);
          const float zg = sigp(bZ[j] + c1);
          const float ng = fmaf(2.f, sigp(fmaf(rg, bGh[j] + c3, bGi[j] + c2)), -1.f);
          hm[j] = fmaf(zg, hm[j] - ng, ng);
          h1L[wb][wofs[j]] = f2bf(hm[j]);
        }
      }
    }
    __syncthreads();
  }
}

// ---------------------------------------------------------------------------
// Final combine: out[b,t] = sigmoid(dec1[b,t] + dec2[b,min(t+10,511)] + b_o)
// ---------------------------------------------------------------------------
__global__ __launch_bounds__(512)
void combine_kernel(const float* __restrict__ dec1, const float* __restrict__ dec2,
                    const float* __restrict__ b_o, float* __restrict__ out)
{
  const int b = blockIdx.x, t = threadIdx.x;
  const int dt = (t + DLY_ < L_) ? t + DLY_ : L_ - 1;
  out[(size_t)b * L_ + t] = sigm(dec1[(size_t)b * L_ + t] + dec2[(size_t)b * L_ + dt] + b_o[0]);
}

extern "C" void kernel_launch(void* const* d_in, const int* in_sizes, int n_in,
                              void* d_out, int out_size, void* d_ws, size_t ws_size,
                              hipStream_t stream) {
  const float* recv   = (const float*)d_in[0];
  const float* wih1l0 = (const float*)d_in[1];
  const float* whh1l0 = (const float*)d_in[2];
  const float* bih1l0 = (const float*)d_in[3];
  const float* bhh1l0 = (const float*)d_in[4];
  const float* wih1l1 = (const float*)d_in[5];
  const float* whh1l1 = (const float*)d_in[6];
  const float* bih1l1 = (const float*)d_in[7];
  const float* bhh1l1 = (const float*)d_in[8];
  const float* wih2l0 = (const float*)d_in[9];
  const float* whh2l0 = (const float*)d_in[10];
  const float* bih2l0 = (const float*)d_in[11];
  const float* bhh2l0 = (const float*)d_in[12];
  const float* wih2l1 = (const float*)d_in[13];
  const float* whh2l1 = (const float*)d_in[14];
  const float* bih2l1 = (const float*)d_in[15];
  const float* bhh2l1 = (const float*)d_in[16];
  const float* w_a    = (const float*)d_in[17];
  const float* b_a    = (const float*)d_in[18]; (void)b_a; // uniform: cancels in softmax
  const float* w_c    = (const float*)d_in[19];
  const float* b_c    = (const float*)d_in[20];
  const float* w_o    = (const float*)d_in[21];
  const float* b_o    = (const float*)d_in[22];
  // d_in[23]=attn_num(5), d_in[24]=d_delay(10): compile-time constants here

  float* dec1 = (float*)d_ws;                 // (B,L) fp32 decoder partial, stack1
  float* dec2 = dec1 + (size_t)B_ * L_;       // (B,L) fp32 decoder partial, stack2

  gru_stack_kernel<<<128, 1024, 0, stream>>>(
      recv,
      wih1l0, whh1l0, bih1l0, bhh1l0, wih1l1, whh1l1, bih1l1, bhh1l1,
      wih2l0, whh2l0, bih2l0, bhh2l0, wih2l1, whh2l1, bih2l1, bhh2l1,
      w_a, w_c, b_c, w_o, dec1, dec2);

  combine_kernel<<<B_, 512, 0, stream>>>(dec1, dec2, b_o, (float*)d_out);
}